// Round 1
// baseline (182.428 us; speedup 1.0000x reference)
//
#include <hip/hip_runtime.h>

// Problem constants (from reference setup_inputs)
#define B_   32
#define T_   4096
#define D_   128
#define TU   512
#define M_   8
#define O_   64      // Dout
#define DCH  16      // D-chunk per block
#define NCH  8       // number of D-chunks (D_/DCH)
#define PAD  17      // LDS leading-dim pad: (17u+d)%32 conflict-free both phases
#define BN_EPS 1e-5f

// ---------------------------------------------------------------------------
// K1: fold BN + conv + fc into Weff[8][128] and beff[8], stored in ws.
//   Wraw[m][d] = sum_o fc_w[m][o]*conv_w[o][d]
//   scale[d]   = gamma[d]*rsqrt(var[d]+eps); shift[d] = beta[d]-mean[d]*scale[d]
//   Weff[m][d] = scale[d]*Wraw[m][d]
//   beff[m]    = fc_b[m] + sum_o fc_w[m][o]*conv_b[o] + sum_d shift[d]*Wraw[m][d]
// ws layout (floats): [0,1024) Weff, [1024,1032) beff
// ---------------------------------------------------------------------------
__global__ void prep_kernel(const float* __restrict__ bn_gamma,
                            const float* __restrict__ bn_beta,
                            const float* __restrict__ bn_mean,
                            const float* __restrict__ bn_var,
                            const float* __restrict__ conv_w,
                            const float* __restrict__ conv_b,
                            const float* __restrict__ fc_w,
                            const float* __restrict__ fc_b,
                            float* __restrict__ ws) {
    __shared__ float wraw[M_ * D_];
    __shared__ float shift_s[D_];
    int tid = threadIdx.x;  // 256 threads
    for (int p = tid; p < M_ * D_; p += 256) {
        int m = p >> 7, d = p & (D_ - 1);
        float s = 0.f;
        for (int o = 0; o < O_; ++o) s += fc_w[m * O_ + o] * conv_w[o * D_ + d];
        wraw[p] = s;
        float sc = bn_gamma[d] * rsqrtf(bn_var[d] + BN_EPS);
        ws[p] = s * sc;
    }
    if (tid < D_) {
        float sc = bn_gamma[tid] * rsqrtf(bn_var[tid] + BN_EPS);
        shift_s[tid] = bn_beta[tid] - bn_mean[tid] * sc;
    }
    __syncthreads();
    if (tid < M_) {
        float s = fc_b[tid];
        for (int o = 0; o < O_; ++o) s += fc_w[tid * O_ + o] * conv_b[o];
        for (int d = 0; d < D_; ++d) s += shift_s[d] * wraw[tid * D_ + d];
        ws[M_ * D_ + tid] = s;
    }
}

// ---------------------------------------------------------------------------
// K2: out[b,u,m] = beff[m]  (full overwrite; scatter kernel atomicAdds on top)
// ---------------------------------------------------------------------------
__global__ void init_out_kernel(const float* __restrict__ ws,
                                float* __restrict__ out) {
    int i = blockIdx.x * 256 + threadIdx.x;  // grid covers B_*TU*M_ exactly
    out[i] = ws[M_ * D_ + (i & (M_ - 1))];
}

// ---------------------------------------------------------------------------
// K3: per-(batch b, d-chunk c) block:
//   phase 1: scatter-max masked positive feats into LDS hidden[512][16] (uint bits)
//   phase 2: partial[u][m] = sum_{d in chunk} hidden[u][d]*Weff[m][d], atomicAdd out
// hidden init=0 and all contributions clamped below by 0 => only fv>0 matter,
// and uint-bit atomicMax == float max for non-negative floats.
// ---------------------------------------------------------------------------
__global__ __launch_bounds__(1024) void scatter_mm_kernel(
    const float* __restrict__ x,        // (B,T,129): [...,0]=tw, [...,1:]=feats
    const int*   __restrict__ mask,     // (B,T) as int32
    const float* __restrict__ tw_uniq,  // (B,Tu)
    const float* __restrict__ ws,       // Weff + beff
    float*       __restrict__ out) {    // (B,Tu,M)
    __shared__ unsigned hid[TU * PAD];  // 34,816 B
    __shared__ float wsm[M_ * DCH];
    const int c = blockIdx.x;   // 0..7
    const int b = blockIdx.y;   // 0..31
    const int tid = threadIdx.x;

    for (int p = tid; p < TU * PAD; p += 1024) hid[p] = 0u;
    if (tid < M_ * DCH) {
        int m = tid / DCH, d = tid % DCH;
        wsm[tid] = ws[m * D_ + c * DCH + d];
    }
    __syncthreads();

    const float* xb = x + (size_t)b * T_ * (D_ + 1);
    const int*   mb = mask + b * T_;
    const float  u0 = tw_uniq[b * TU];

    const int dl = tid & (DCH - 1);   // 0..15: d within chunk
    const int g  = tid >> 4;          // 0..63: row group
    for (int t = g; t < T_; t += 64) {
        const float* row = xb + (size_t)t * (D_ + 1);
        float fv  = row[1 + c * DCH + dl];
        float twf = row[0];           // broadcast within the 16-lane group
        int   mk  = mb[t];
        if (mk != 0 && fv > 0.0f) {
            int u = (int)(twf - u0);
            u = min(max(u, 0), TU - 1);
            atomicMax(&hid[u * PAD + dl], __float_as_uint(fv));
        }
    }
    __syncthreads();

    // epilogue: thread -> (u = tid&511, mh = tid>>9 selects m in [4*mh, 4*mh+4))
    const int u  = tid & (TU - 1);
    const int mh = tid >> 9;
    float a0 = 0.f, a1 = 0.f, a2 = 0.f, a3 = 0.f;
#pragma unroll
    for (int d = 0; d < DCH; ++d) {
        float h = __uint_as_float(hid[u * PAD + d]);  // (17u+d)%32: conflict-free
        a0 += h * wsm[(mh * 4 + 0) * DCH + d];
        a1 += h * wsm[(mh * 4 + 1) * DCH + d];
        a2 += h * wsm[(mh * 4 + 2) * DCH + d];
        a3 += h * wsm[(mh * 4 + 3) * DCH + d];
    }
    float* op = out + ((size_t)(b * TU + u)) * M_ + mh * 4;
    atomicAdd(op + 0, a0);
    atomicAdd(op + 1, a1);
    atomicAdd(op + 2, a2);
    atomicAdd(op + 3, a3);
}

extern "C" void kernel_launch(void* const* d_in, const int* in_sizes, int n_in,
                              void* d_out, int out_size, void* d_ws, size_t ws_size,
                              hipStream_t stream) {
    const float* x        = (const float*)d_in[0];   // (32,4096,129) f32
    const int*   mask     = (const int*)  d_in[1];   // (32,4096,1) bool->int32
    const float* tw_uniq  = (const float*)d_in[2];   // (32,512,1) f32
    const float* bn_gamma = (const float*)d_in[3];
    const float* bn_beta  = (const float*)d_in[4];
    const float* bn_mean  = (const float*)d_in[5];
    const float* bn_var   = (const float*)d_in[6];
    const float* conv_w   = (const float*)d_in[7];   // (64,128)
    const float* conv_b   = (const float*)d_in[8];   // (64,)
    const float* fc_w     = (const float*)d_in[9];   // (8,64)
    const float* fc_b     = (const float*)d_in[10];  // (8,)
    float* ws  = (float*)d_ws;
    float* out = (float*)d_out;                      // (32,512,8) f32

    prep_kernel<<<1, 256, 0, stream>>>(bn_gamma, bn_beta, bn_mean, bn_var,
                                       conv_w, conv_b, fc_w, fc_b, ws);
    init_out_kernel<<<(B_ * TU * M_) / 256, 256, 0, stream>>>(ws, out);
    scatter_mm_kernel<<<dim3(NCH, B_), 1024, 0, stream>>>(x, mask, tw_uniq, ws, out);
}